// Round 1
// baseline (284.358 us; speedup 1.0000x reference)
//
#include <hip/hip_runtime.h>

// DynamicHead: varying-coefficient MLP.
//   basis(t) in R^12; layer: out[b,o] = sum_s basis[b,s]*( sum_i x[b,i]*W[s,i,o] + bias[s,o] )
// Strategy: per s, K=256 bf16 MFMA pass (A = X tile in LDS, B = W_s pre-packed in
// MFMA-native fragment order, loaded straight from global/L2), then fp32 scale-add
// out += basis_s*(acc_s + bias_s). relu + bf16 store for layers 0/1; final layer is a
// small reduction kernel (out dim = 1).

typedef __attribute__((ext_vector_type(8))) short short8;
typedef __attribute__((ext_vector_type(4))) float floatx4;

#define BB 32768
#define XPAD 264  // 256 + 8 shorts pad -> row stride 528 B, even LDS bank spread

__device__ __forceinline__ short f2bf(float f){
  unsigned u = __float_as_uint(f);
  u = u + 0x7fffu + ((u >> 16) & 1u);   // RNE
  return (short)(u >> 16);
}
__device__ __forceinline__ float bf2f(short s){
  return __uint_as_float(((unsigned)(unsigned short)s) << 16);
}

__device__ __forceinline__ void make_basis(float t, float* p){
  p[0] = 1.f; p[1] = t; p[2] = t*t; p[3] = p[2]*t;
  const float knots[8] = {1.f/9.f, 2.f/9.f, 3.f/9.f, 4.f/9.f,
                          5.f/9.f, 6.f/9.f, 7.f/9.f, 8.f/9.f};
  #pragma unroll
  for (int j = 0; j < 8; ++j){
    float d = t - knots[j];
    d = fmaxf(d, 0.f);
    p[4+j] = d*d*d;
  }
}

// Repack W (12, 256, 256) fp32 -> bf16 in MFMA B-frag native order:
// Wp[((s*8+ko)*16+ntg)*512 + (q*16+n16)*8 + j] = bf16( W[s][ko*32+q*8+j][ntg*16+n16] )
__global__ void pack_w_kernel(const float* __restrict__ W, short* __restrict__ Wp){
  int p = blockIdx.x * 256 + threadIdx.x;
  int j   = p & 7;
  int n16 = (p >> 3) & 15;
  int q   = (p >> 7) & 3;
  int ntg = (p >> 9) & 15;
  int ko  = (p >> 13) & 7;
  int s   = p >> 16;
  int i = ko*32 + q*8 + j;
  int o = ntg*16 + n16;
  Wp[p] = f2bf(W[s*65536 + i*256 + o]);
}

// Block tile: BM=64 rows x BN=128 cols, 4 waves (2x2 of 32x64 wave tiles).
// Grid: (32768/64, 256/128) = (512, 2).
template<bool IN_F32>
__global__ __launch_bounds__(256, 2)
void layer_kernel(const void* __restrict__ in_v, const float* __restrict__ treat,
                  const short* __restrict__ Wp, const float* __restrict__ bias,
                  short* __restrict__ out){
  __shared__ short Xlds[64 * XPAD];   // 33792 B
  __shared__ float blds[12 * 64];     // basis, [s][m]

  const int tid  = threadIdx.x;
  const int m0   = blockIdx.x * 64;
  const int n0   = blockIdx.y * 128;
  const int lane = tid & 63;
  const int wid  = tid >> 6;
  const int wm   = wid >> 1;          // 0..1 (m offset wm*32)
  const int wn   = wid & 1;           // 0..1 (n offset wn*64)
  const int q    = lane >> 4;
  const int l16  = lane & 15;

  // ---- stage X tile into LDS (bf16, padded rows) ----
  if (IN_F32){
    const float* X = (const float*)in_v;
    #pragma unroll
    for (int it = 0; it < 16; ++it){
      int idx = it * 256 + tid;        // 64 rows x 64 chunks of 4 floats
      int m = idx >> 6, c = idx & 63;
      float4 v = *(const float4*)(X + (size_t)(m0 + m) * 256 + c * 4);
      short4 sv;
      sv.x = f2bf(v.x); sv.y = f2bf(v.y); sv.z = f2bf(v.z); sv.w = f2bf(v.w);
      *(short4*)&Xlds[m * XPAD + c * 4] = sv;
    }
  } else {
    const short* X = (const short*)in_v;
    #pragma unroll
    for (int it = 0; it < 8; ++it){
      int idx = it * 256 + tid;        // 64 rows x 32 chunks of 8 shorts
      int m = idx >> 5, c = idx & 31;
      short8 v = *(const short8*)(X + (size_t)(m0 + m) * 256 + c * 8);
      *(short8*)&Xlds[m * XPAD + c * 8] = v;
    }
  }
  if (tid < 64){
    float t = treat[m0 + tid];
    float p[12]; make_basis(t, p);
    #pragma unroll
    for (int s = 0; s < 12; ++s) blds[s * 64 + tid] = p[s];
  }
  __syncthreads();

  const int ntg0 = blockIdx.y * 8 + wn * 4;   // global 16-col tile index base
  const floatx4 zero = {0.f, 0.f, 0.f, 0.f};
  floatx4 out_acc[2][4];
  #pragma unroll
  for (int mt = 0; mt < 2; ++mt)
    #pragma unroll
    for (int nt = 0; nt < 4; ++nt) out_acc[mt][nt] = zero;

  for (int s = 0; s < 12; ++s){
    // prefetch bias + basis for this s (used after the K loop)
    float bv[4];
    #pragma unroll
    for (int nt = 0; nt < 4; ++nt)
      bv[nt] = bias[s * 256 + n0 + wn * 64 + nt * 16 + l16];
    floatx4 bas[2];
    #pragma unroll
    for (int mt = 0; mt < 2; ++mt)
      bas[mt] = *(const floatx4*)&blds[s * 64 + wm * 32 + mt * 16 + q * 4];

    const short* wb = Wp + (size_t)s * 65536 + ntg0 * 512 + lane * 8;

    floatx4 acc[2][4];
    #pragma unroll
    for (int mt = 0; mt < 2; ++mt)
      #pragma unroll
      for (int nt = 0; nt < 4; ++nt) acc[mt][nt] = zero;

    short8 a_c[2], b_c[4];
    #pragma unroll
    for (int mt = 0; mt < 2; ++mt)
      a_c[mt] = *(const short8*)&Xlds[(wm*32 + mt*16 + l16) * XPAD + q * 8];
    #pragma unroll
    for (int nt = 0; nt < 4; ++nt)
      b_c[nt] = *(const short8*)(wb + nt * 512);

    #pragma unroll
    for (int ko = 0; ko < 8; ++ko){
      short8 a_n[2], b_n[4];
      if (ko < 7){
        #pragma unroll
        for (int mt = 0; mt < 2; ++mt)
          a_n[mt] = *(const short8*)&Xlds[(wm*32 + mt*16 + l16) * XPAD + (ko+1)*32 + q * 8];
        #pragma unroll
        for (int nt = 0; nt < 4; ++nt)
          b_n[nt] = *(const short8*)(wb + (ko+1) * 8192 + nt * 512);
      }
      #pragma unroll
      for (int mt = 0; mt < 2; ++mt)
        #pragma unroll
        for (int nt = 0; nt < 4; ++nt)
          acc[mt][nt] = __builtin_amdgcn_mfma_f32_16x16x32_bf16(
              a_c[mt], b_c[nt], acc[mt][nt], 0, 0, 0);
      if (ko < 7){
        #pragma unroll
        for (int mt = 0; mt < 2; ++mt) a_c[mt] = a_n[mt];
        #pragma unroll
        for (int nt = 0; nt < 4; ++nt) b_c[nt] = b_n[nt];
      }
    }

    // out += basis_s * (acc_s + bias_s)
    #pragma unroll
    for (int mt = 0; mt < 2; ++mt)
      #pragma unroll
      for (int nt = 0; nt < 4; ++nt)
        #pragma unroll
        for (int r = 0; r < 4; ++r)
          out_acc[mt][nt][r] += bas[mt][r] * (acc[mt][nt][r] + bv[nt]);
  }

  // epilogue: relu + bf16 store. C/D layout: col=lane&15, row=(lane>>4)*4+reg.
  #pragma unroll
  for (int mt = 0; mt < 2; ++mt){
    #pragma unroll
    for (int nt = 0; nt < 4; ++nt){
      int col = n0 + wn * 64 + nt * 16 + l16;
      #pragma unroll
      for (int r = 0; r < 4; ++r){
        int row = m0 + wm * 32 + mt * 16 + q * 4 + r;
        float vv = fmaxf(out_acc[mt][nt][r], 0.f);
        out[(size_t)row * 256 + col] = f2bf(vv);
      }
    }
  }
}

// Final layer (out dim 1): one wave per row, W2 staged in LDS. 64 rows/block.
__global__ __launch_bounds__(256)
void final_kernel(const short* __restrict__ X2, const float* __restrict__ treat,
                  const float* __restrict__ W2, const float* __restrict__ b2,
                  float* __restrict__ out){
  __shared__ float w2l[12 * 256];
  __shared__ float b2l[12];
  const int tid = threadIdx.x;
  const int m0 = blockIdx.x * 64;
  #pragma unroll
  for (int it = 0; it < 12; ++it) w2l[it * 256 + tid] = W2[it * 256 + tid];
  if (tid < 12) b2l[tid] = b2[tid];
  __syncthreads();
  const int lane = tid & 63, wid = tid >> 6;
  for (int rr = 0; rr < 16; ++rr){
    int b = m0 + wid * 16 + rr;
    float t = treat[b];
    float p[12]; make_basis(t, p);
    const short* xr = X2 + (size_t)b * 256 + lane * 4;
    short4 xv = *(const short4*)xr;
    float xs[4] = { bf2f(xv.x), bf2f(xv.y), bf2f(xv.z), bf2f(xv.w) };
    float ws[4] = {0.f, 0.f, 0.f, 0.f};
    #pragma unroll
    for (int s = 0; s < 12; ++s){
      floatx4 w4 = *(const floatx4*)&w2l[s * 256 + lane * 4];
      #pragma unroll
      for (int j = 0; j < 4; ++j) ws[j] += p[s] * w4[j];
    }
    float dot = xs[0]*ws[0] + xs[1]*ws[1] + xs[2]*ws[2] + xs[3]*ws[3];
    #pragma unroll
    for (int off = 32; off > 0; off >>= 1) dot += __shfl_down(dot, off, 64);
    if (lane == 0){
      float bb = 0.f;
      #pragma unroll
      for (int s = 0; s < 12; ++s) bb += p[s] * b2l[s];
      out[b] = dot + bb;
    }
  }
}

extern "C" void kernel_launch(void* const* d_in, const int* in_sizes, int n_in,
                              void* d_out, int out_size, void* d_ws, size_t ws_size,
                              hipStream_t stream){
  const float* treat = (const float*)d_in[0];
  const float* feat  = (const float*)d_in[1];
  const float* W0    = (const float*)d_in[2];
  const float* b0    = (const float*)d_in[3];
  const float* W1    = (const float*)d_in[4];
  const float* b1    = (const float*)d_in[5];
  const float* W2    = (const float*)d_in[6];
  const float* b2    = (const float*)d_in[7];

  char* ws = (char*)d_ws;
  short* Wp0 = (short*)(ws);                     // 1,572,864 B
  short* Wp1 = (short*)(ws + 1572864);           // 1,572,864 B
  short* X1  = (short*)(ws + 3145728);           // 16,777,216 B
  short* X2  = (short*)(ws + 19922944);          // 16,777,216 B  (total ~35 MB)
  float* out = (float*)d_out;

  pack_w_kernel<<<3072, 256, 0, stream>>>(W0, Wp0);
  pack_w_kernel<<<3072, 256, 0, stream>>>(W1, Wp1);
  layer_kernel<true ><<<dim3(512, 2), 256, 0, stream>>>((const void*)feat, treat, Wp0, b0, X1);
  layer_kernel<false><<<dim3(512, 2), 256, 0, stream>>>((const void*)X1,  treat, Wp1, b1, X2);
  final_kernel<<<512, 256, 0, stream>>>(X2, treat, W2, b2, out);
}